// Round 3
// baseline (2251.200 us; speedup 1.0000x reference)
//
#include <hip/hip_runtime.h>
#include <hip/hip_bf16.h>

// Problem constants
#define NB 64    // batch
#define TT 512   // timesteps
#define HH 512   // hidden
#define DD 512   // input dim

typedef __attribute__((ext_vector_type(8))) __bf16 bf16x8;
typedef __attribute__((ext_vector_type(4))) float f32x4;

__device__ __forceinline__ unsigned short f2bf_rn(float f) {
    union { float f; unsigned u; } v; v.f = f;
    unsigned r = v.u + 0x7FFFu + ((v.u >> 16) & 1u);
    return (unsigned short)(r >> 16);
}
__device__ __forceinline__ float bf2f(unsigned short s) {
    union { unsigned u; float f; } v; v.u = ((unsigned)s) << 16;
    return v.f;
}

// ---------------------------------------------------------------------------
// Kernel 1: Wt[n][k]   = bf16_hi(Wx[k][n]),  Wt[n][512+k] = bf16_lo(Wx[k][n])
// (unchanged from round 1 — passed)
// ---------------------------------------------------------------------------
__global__ __launch_bounds__(256) void wt_kernel(const float* __restrict__ Wx,
                                                 unsigned short* __restrict__ Wt) {
    const int bk = blockIdx.x >> 3, bn = blockIdx.x & 7;
    const int k0 = bk * 64, n0 = bn * 64;
    __shared__ float tile[64][65];
    const int t = threadIdx.x;
    const int kr = t >> 2, seg = t & 3;
    const float4* src = (const float4*)&Wx[(k0 + kr) * HH + n0 + seg * 16];
    float4 a = src[0], b = src[1], c = src[2], d = src[3];
    float vv[16];
    *(float4*)&vv[0] = a; *(float4*)&vv[4] = b; *(float4*)&vv[8] = c; *(float4*)&vv[12] = d;
#pragma unroll
    for (int q = 0; q < 16; ++q) tile[kr][seg * 16 + q] = vv[q];
    __syncthreads();
    const int nr = t >> 2;
    unsigned hu[8], lu[8];
#pragma unroll
    for (int i = 0; i < 8; ++i) {
        float f0 = tile[seg * 16 + 2 * i + 0][nr];
        float f1 = tile[seg * 16 + 2 * i + 1][nr];
        unsigned short h0 = f2bf_rn(f0); unsigned short l0 = f2bf_rn(f0 - bf2f(h0));
        unsigned short h1 = f2bf_rn(f1); unsigned short l1 = f2bf_rn(f1 - bf2f(h1));
        hu[i] = (unsigned)h0 | ((unsigned)h1 << 16);
        lu[i] = (unsigned)l0 | ((unsigned)l1 << 16);
    }
    unsigned short* dh = &Wt[(n0 + nr) * 1024 + k0 + seg * 16];
    unsigned short* dl = dh + 512;
    ((uint4*)dh)[0] = make_uint4(hu[0], hu[1], hu[2], hu[3]);
    ((uint4*)dh)[1] = make_uint4(hu[4], hu[5], hu[6], hu[7]);
    ((uint4*)dl)[0] = make_uint4(lu[0], lu[1], lu[2], lu[3]);
    ((uint4*)dl)[1] = make_uint4(lu[4], lu[5], lu[6], lu[7]);
}

// ---------------------------------------------------------------------------
// Kernel 2: projection GEMM  out[i][j] = sum_k x[i][k]*Wx[k][j] + b[j]
// split-bf16 (hi*hi + hi*lo + lo*hi) via MFMA. (unchanged — passed)
// ---------------------------------------------------------------------------
#define LDA 72
__global__ __launch_bounds__(256) void proj_kernel(const float* __restrict__ x,
                                                   const unsigned short* __restrict__ Wt,
                                                   const float* __restrict__ bias,
                                                   float* __restrict__ out) {
    __shared__ __align__(16) unsigned short a_hi[64 * LDA];
    __shared__ __align__(16) unsigned short a_lo[64 * LDA];
    __shared__ __align__(16) unsigned short b_hi[64 * LDA];
    __shared__ __align__(16) unsigned short b_lo[64 * LDA];

    const int bx = blockIdx.x;
    const int i0 = (bx >> 3) * 64;
    const int n0 = (bx & 7) * 64;
    const int t = threadIdx.x;
    const int row = t >> 2, seg = t & 3;
    const int lane = t & 63, wid = t >> 6;
    const int wm = (wid >> 1) * 32, wn = (wid & 1) * 32;
    const int fr = lane & 15;

    f32x4 acc00 = {0.f, 0.f, 0.f, 0.f}, acc01 = acc00, acc10 = acc00, acc11 = acc00;

    for (int kc = 0; kc < 8; ++kc) {
        __syncthreads();
        {
            const float4* src = (const float4*)&x[(i0 + row) * DD + kc * 64 + seg * 16];
            float4 a = src[0], b = src[1], c = src[2], d = src[3];
            float vv[16];
            *(float4*)&vv[0] = a; *(float4*)&vv[4] = b; *(float4*)&vv[8] = c; *(float4*)&vv[12] = d;
            unsigned hu[8], lu[8];
#pragma unroll
            for (int i = 0; i < 8; ++i) {
                unsigned short h0 = f2bf_rn(vv[2 * i]); unsigned short l0 = f2bf_rn(vv[2 * i] - bf2f(h0));
                unsigned short h1 = f2bf_rn(vv[2 * i + 1]); unsigned short l1 = f2bf_rn(vv[2 * i + 1] - bf2f(h1));
                hu[i] = (unsigned)h0 | ((unsigned)h1 << 16);
                lu[i] = (unsigned)l0 | ((unsigned)l1 << 16);
            }
            uint4* dh = (uint4*)&a_hi[row * LDA + seg * 16];
            uint4* dl = (uint4*)&a_lo[row * LDA + seg * 16];
            dh[0] = make_uint4(hu[0], hu[1], hu[2], hu[3]);
            dh[1] = make_uint4(hu[4], hu[5], hu[6], hu[7]);
            dl[0] = make_uint4(lu[0], lu[1], lu[2], lu[3]);
            dl[1] = make_uint4(lu[4], lu[5], lu[6], lu[7]);
        }
        {
            const uint4* sh = (const uint4*)&Wt[(n0 + row) * 1024 + kc * 64 + seg * 16];
            const uint4* sl = (const uint4*)&Wt[(n0 + row) * 1024 + 512 + kc * 64 + seg * 16];
            uint4 h0v = sh[0], h1v = sh[1], l0v = sl[0], l1v = sl[1];
            uint4* dh = (uint4*)&b_hi[row * LDA + seg * 16];
            uint4* dl = (uint4*)&b_lo[row * LDA + seg * 16];
            dh[0] = h0v; dh[1] = h1v; dl[0] = l0v; dl[1] = l1v;
        }
        __syncthreads();
#pragma unroll
        for (int s = 0; s < 2; ++s) {
            const int ko = s * 32 + (lane >> 4) * 8;
            bf16x8 ah0 = *(const bf16x8*)&a_hi[(wm + fr) * LDA + ko];
            bf16x8 ah1 = *(const bf16x8*)&a_hi[(wm + 16 + fr) * LDA + ko];
            bf16x8 al0 = *(const bf16x8*)&a_lo[(wm + fr) * LDA + ko];
            bf16x8 al1 = *(const bf16x8*)&a_lo[(wm + 16 + fr) * LDA + ko];
            bf16x8 bh0 = *(const bf16x8*)&b_hi[(wn + fr) * LDA + ko];
            bf16x8 bh1 = *(const bf16x8*)&b_hi[(wn + 16 + fr) * LDA + ko];
            bf16x8 bl0 = *(const bf16x8*)&b_lo[(wn + fr) * LDA + ko];
            bf16x8 bl1 = *(const bf16x8*)&b_lo[(wn + 16 + fr) * LDA + ko];
            acc00 = __builtin_amdgcn_mfma_f32_16x16x32_bf16(ah0, bh0, acc00, 0, 0, 0);
            acc00 = __builtin_amdgcn_mfma_f32_16x16x32_bf16(ah0, bl0, acc00, 0, 0, 0);
            acc00 = __builtin_amdgcn_mfma_f32_16x16x32_bf16(al0, bh0, acc00, 0, 0, 0);
            acc01 = __builtin_amdgcn_mfma_f32_16x16x32_bf16(ah0, bh1, acc01, 0, 0, 0);
            acc01 = __builtin_amdgcn_mfma_f32_16x16x32_bf16(ah0, bl1, acc01, 0, 0, 0);
            acc01 = __builtin_amdgcn_mfma_f32_16x16x32_bf16(al0, bh1, acc01, 0, 0, 0);
            acc10 = __builtin_amdgcn_mfma_f32_16x16x32_bf16(ah1, bh0, acc10, 0, 0, 0);
            acc10 = __builtin_amdgcn_mfma_f32_16x16x32_bf16(ah1, bl0, acc10, 0, 0, 0);
            acc10 = __builtin_amdgcn_mfma_f32_16x16x32_bf16(al1, bh0, acc10, 0, 0, 0);
            acc11 = __builtin_amdgcn_mfma_f32_16x16x32_bf16(ah1, bh1, acc11, 0, 0, 0);
            acc11 = __builtin_amdgcn_mfma_f32_16x16x32_bf16(ah1, bl1, acc11, 0, 0, 0);
            acc11 = __builtin_amdgcn_mfma_f32_16x16x32_bf16(al1, bh1, acc11, 0, 0, 0);
        }
    }
    const float bc0 = bias[n0 + wn + fr];
    const float bc1 = bias[n0 + wn + 16 + fr];
#pragma unroll
    for (int r = 0; r < 4; ++r) {
        int rw0 = i0 + wm + (lane >> 4) * 4 + r;
        int rw1 = rw0 + 16;
        out[rw0 * HH + n0 + wn + fr]      = acc00[r] + bc0;
        out[rw0 * HH + n0 + wn + 16 + fr] = acc01[r] + bc1;
        out[rw1 * HH + n0 + wn + fr]      = acc10[r] + bc0;
        out[rw1 * HH + n0 + wn + 16 + fr] = acc11[r] + bc1;
    }
}

// ---------------------------------------------------------------------------
// Kernel 3: recurrence. grid 256 x 1024 threads, exactly 1 block/CU (VGPR cap
// 128 via __launch_bounds__(1024,4)), all 256 blocks co-resident.
// block b: batch g = b & 63, col slice s = b >> 6 (cols [s*128, s*128+128)).
// Thread (jl = tid&127, kg = tid>>7): holds Wh[kg*64 .. kg*64+64)[j] in 16
// NAMED float4 registers (64 VGPRs — named vars cannot be demoted to scratch,
// unlike arrays, which promote-alloca refused in rounds 1-2: VGPR_Count=80).
// Sync: per-(parity,batch,slice) int flag = step number. 4 pollers/block only
// (relaxed agent loads, signed >=; 0xAA poison is negative -> blocks).
// Producer: 128 relaxed agent data stores -> __syncthreads (vmcnt(0) drain)
// -> single release flag store. Deadlock-free: producer can only overwrite a
// parity slot t-2 -> t after all peers published t-1, which required their
// t-2 reads to have completed.
// ---------------------------------------------------------------------------
__global__ __launch_bounds__(1024, 4) void rec_kernel(const float* __restrict__ h0,
                                                      const float* __restrict__ Wh,
                                                      float* __restrict__ out,
                                                      float* __restrict__ hbuf,
                                                      int* __restrict__ flags) {
    const int b = blockIdx.x;
    const int g = b & 63;        // batch row
    const int s = b >> 6;        // col slice
    const int tid = threadIdx.x;
    const int jl = tid & 127;    // local col
    const int kg = tid >> 7;     // k-chunk, wave-uniform (2 waves per kg)
    const int kb = kg * 64;
    const int j = s * 128 + jl;  // global col

    // ---- one-time: Wh chunk into 16 named float4 regs (64 VGPRs) ----
#define WDECL(i)                                        \
    float4 w##i;                                        \
    w##i.x = Wh[(kb + 4 * i + 0) * HH + j];             \
    w##i.y = Wh[(kb + 4 * i + 1) * HH + j];             \
    w##i.z = Wh[(kb + 4 * i + 2) * HH + j];             \
    w##i.w = Wh[(kb + 4 * i + 3) * HH + j];
    WDECL(0)  WDECL(1)  WDECL(2)  WDECL(3)
    WDECL(4)  WDECL(5)  WDECL(6)  WDECL(7)
    WDECL(8)  WDECL(9)  WDECL(10) WDECL(11)
    WDECL(12) WDECL(13) WDECL(14) WDECL(15)
#undef WDECL

    __shared__ float hs[HH];
    __shared__ float red[8][128];

#pragma unroll 1
    for (int t = 0; t < TT; ++t) {
        const int p  = t & 1;        // publish parity
        const int pp = 1 - p;        // consume parity (t-1)

        // prefetch xwx for own cols (in flight across the poll/barrier)
        float xw = 0.f;
        if (tid < 128) xw = out[((size_t)g * TT + t) * HH + j];

        if (t == 0) {
            if (tid < HH) hs[tid] = h0[g * HH + tid];
            __syncthreads();
        } else {
            if (tid < 4) {
                int* f = &flags[(pp * NB + g) * 4 + tid];
                const int want = t - 1;
                while (__hip_atomic_load(f, __ATOMIC_RELAXED,
                                         __HIP_MEMORY_SCOPE_AGENT) < want) {
                }
            }
            __syncthreads();  // B1: flags observed
            if (tid < HH) {
                // L1-bypassing loads; data is at LLC before flag (vmcnt drain)
                hs[tid] = __hip_atomic_load(&hbuf[(pp * NB + g) * HH + tid],
                                            __ATOMIC_RELAXED,
                                            __HIP_MEMORY_SCOPE_AGENT);
            }
            __syncthreads();  // B2: hs ready
        }

        // ---- partial matvec over this thread's 64-k chunk ----
        // hs addresses are wave-uniform -> 64-lane broadcast, conflict-free
        const float4* h4 = (const float4*)&hs[kb];
        float a0 = 0.f, a1 = 0.f, a2 = 0.f, a3 = 0.f;
#define WFMA(i)                                 \
        {                                       \
            float4 hv = h4[i];                  \
            a0 = fmaf(w##i.x, hv.x, a0);        \
            a1 = fmaf(w##i.y, hv.y, a1);        \
            a2 = fmaf(w##i.z, hv.z, a2);        \
            a3 = fmaf(w##i.w, hv.w, a3);        \
        }
        WFMA(0)  WFMA(1)  WFMA(2)  WFMA(3)
        WFMA(4)  WFMA(5)  WFMA(6)  WFMA(7)
        WFMA(8)  WFMA(9)  WFMA(10) WFMA(11)
        WFMA(12) WFMA(13) WFMA(14) WFMA(15)
#undef WFMA
        red[kg][jl] = (a0 + a1) + (a2 + a3);
        __syncthreads();  // B3: red ready

        // ---- reduce 8 partials, tanh, publish data ----
        if (tid < 128) {
            float v = xw;
#pragma unroll
            for (int k = 0; k < 8; ++k) v += red[k][jl];
            float hn = 1.f - 2.f / (__expf(2.f * v) + 1.f);
            out[((size_t)g * TT + t) * HH + j] = hn;
            __hip_atomic_store(&hbuf[(p * NB + g) * HH + j], hn,
                               __ATOMIC_RELAXED, __HIP_MEMORY_SCOPE_AGENT);
        }
        __syncthreads();  // B4: vmcnt(0) drain -> data at LLC; red/hs reusable
        if (tid == 0)
            __hip_atomic_store(&flags[(p * NB + g) * 4 + s], t,
                               __ATOMIC_RELEASE, __HIP_MEMORY_SCOPE_AGENT);
    }
}

// ---------------------------------------------------------------------------
extern "C" void kernel_launch(void* const* d_in, const int* in_sizes, int n_in,
                              void* d_out, int out_size, void* d_ws, size_t ws_size,
                              hipStream_t stream) {
    (void)in_sizes; (void)n_in; (void)out_size; (void)ws_size;
    const float* x  = (const float*)d_in[0];
    const float* h0 = (const float*)d_in[1];
    const float* Wx = (const float*)d_in[2];
    const float* Wh = (const float*)d_in[3];
    const float* bv = (const float*)d_in[4];
    float* out = (float*)d_out;

    // workspace layout (0xAA poison: flag ints are negative -> pollers block)
    int*   flags = (int*)d_ws;                                   // 2*64*4*4 = 2 KiB
    float* hbuf  = (float*)((char*)d_ws + 4096);                 // 2*64*512*4 = 256 KiB
    unsigned short* Wt = (unsigned short*)((char*)d_ws + 4096 + 2 * NB * HH * 4); // 1 MiB

    // 1) split+transpose Wx -> Wt (bf16 hi|lo, B^T layout)
    wt_kernel<<<64, 256, 0, stream>>>(Wx, Wt);

    // 2) projection GEMM: d_out = x @ Wx + b  (split-bf16 MFMA, fp32-accurate)
    proj_kernel<<<(32768 / 64) * (HH / 64), 256, 0, stream>>>(x, Wt, bv, out);

    // 3) sequential recurrence, in-place on d_out
    rec_kernel<<<NB * 4, 1024, 0, stream>>>(h0, Wh, out, hbuf, flags);
}